// Round 6
// baseline (199.710 us; speedup 1.0000x reference)
//
#include <hip/hip_runtime.h>

// Round 6: QKV GEMM ported to m201-style 256x256 8-wave schedule:
//   BM=BN=256 BK=64, 8 waves (2M x 4N), wave-tile 128x64 (2x arithmetic
//   intensity of 64x64 -> LDS-read path no longer oversubscribed),
//   2 phases/K-tile (mh halves, 32 MFMA each), per-phase half-tile staging,
//   counted vmcnt(4)/vmcnt(2) (never 0 in steady state), both-sides XOR
//   swizzle, setprio MFMA clusters. LDS 128KB, 1 block/CU, grid 288.
// Proj stays on the 128^2 ring-2 kernel; attention unchanged from round 2.
// Constants: B=8 N=1024 C=768 H=12 D=64 P=16; BH=96; padded KV MKV=1056.

typedef __attribute__((ext_vector_type(8))) short short8;
typedef __attribute__((ext_vector_type(4))) float f32x4;
typedef __attribute__((ext_vector_type(16))) float f32x16;
typedef __attribute__((ext_vector_type(4))) int i32x4;

#define GLOAD_LDS16(g, l)                                              \
    __builtin_amdgcn_global_load_lds(                                  \
        (const __attribute__((address_space(1))) void*)(g),            \
        (__attribute__((address_space(3))) void*)(l), 16, 0, 0)

#define GBAR  asm volatile("s_barrier" ::: "memory")
#define LGKM0 asm volatile("s_waitcnt lgkmcnt(0)" ::: "memory")
#define VMC4  asm volatile("s_waitcnt vmcnt(4)" ::: "memory")
#define VMC2  asm volatile("s_waitcnt vmcnt(2)" ::: "memory")
#define VMC0  asm volatile("s_waitcnt vmcnt(0)" ::: "memory")

__device__ __forceinline__ unsigned short f2b(float f) {
    unsigned u = __builtin_bit_cast(unsigned, f);
    u = (u + 0x7fffu + ((u >> 16) & 1u)) >> 16;
    return (unsigned short)u;
}

__device__ __forceinline__ int cvt_pk_bf16(float lo, float hi) {
    int r;
    asm("v_cvt_pk_bf16_f32 %0, %1, %2" : "=v"(r) : "v"(lo), "v"(hi));
    return r;
}

// ---------------- f32 -> bf16 convert (vectorized) ----------------
__global__ void cvt_f32_to_bf16(const float* __restrict__ in,
                                unsigned short* __restrict__ out, int n4) {
    int i = blockIdx.x * blockDim.x + threadIdx.x;
    int stride = gridDim.x * blockDim.x;
    for (; i < n4; i += stride) {
        float4 v = reinterpret_cast<const float4*>(in)[i];
        ushort4 o;
        o.x = f2b(v.x); o.y = f2b(v.y); o.z = f2b(v.z); o.w = f2b(v.w);
        reinterpret_cast<ushort4*>(out)[i] = o;
    }
}

// ------------- prefix K/V prefill + pad-row zeroing ----------------
__global__ void prefill(const float* __restrict__ pk, const float* __restrict__ pv,
                        unsigned short* __restrict__ kc, unsigned short* __restrict__ vT) {
    int idx = blockIdx.x * 256 + threadIdx.x;   // 96*32*64 total
    int d  = idx & 63;
    int j  = (idx >> 6) & 31;
    int bh = idx >> 11;
    if (bh >= 96) return;
    int h = bh % 12;
    if (j < 16) {
        kc[((size_t)bh * 1056 + j) * 64 + d]  = f2b(pk[j * 768 + h * 64 + d]);
        vT[((size_t)bh * 64 + d) * 1056 + j]  = f2b(pv[j * 768 + h * 64 + d]);
    } else {
        int row = 1040 + (j - 16);
        kc[((size_t)bh * 1056 + row) * 64 + d] = 0;
        vT[((size_t)bh * 64 + d) * 1056 + row] = 0;
    }
}

// ============ 256x256 8-wave QKV GEMM (m201-style schedule) ============
// Y[m][f] = sum_k A[m][k]*W[f][k] + bias[f], scatter epilogue (QKV layouts).
// LDS: L[2 buf][4 part][128*64] bf16; part 0/1 = A rows 0-127/128-255,
//      part 2/3 = B(W) rows 0-127/128-255 of the block tile. 128 KB.
// Swizzle: byte-in-half ^= ((row&4)<<3) applied on global source col and
// on ds_read col (linear gload_lds dest) — involution, both-sides (rule 21).
template<int FT>
__global__ __launch_bounds__(512, 1) void gemm256(
    const unsigned short* __restrict__ A,   // [M][K] bf16
    const unsigned short* __restrict__ W,   // [F][K] bf16
    const float* __restrict__ bias,         // [F]
    int M, int F, int K,
    unsigned short* __restrict__ qbuf,      // [96][1024][64]
    unsigned short* __restrict__ kcbuf,     // [96][1056][64]
    unsigned short* __restrict__ vtbuf)     // [96][64][1056]
{
    __shared__ __align__(16) unsigned short L[2][4][8192];   // 128 KB

    const int tid = threadIdx.x;
    const int bid = (blockIdx.x & 7) * (gridDim.x >> 3) + (blockIdx.x >> 3);
    const int m0 = (bid / FT) * 256;
    const int f0 = (bid % FT) * 256;
    const int wid = tid >> 6, lane = tid & 63;
    const int wm = wid >> 2, wn = wid & 3;      // 2M x 4N, wave-tile 128x64
    const int lo = lane & 15, hi = lane >> 4;
    const int csw = ((lo & 4) << 3);            // read-side swizzle byte XOR

    // stage one half-tile (128 rows x 64 cols) of PART from SRC rows ROFF+row
#define STG(BUF, PART, SRC, ROFF, KT)                                          \
    { _Pragma("unroll") for (int r_ = 0; r_ < 2; ++r_) {                       \
        int c_ = r_ * 512 + tid; int row_ = c_ >> 3;                           \
        int cb_ = ((c_ & 7) * 16) ^ ((row_ & 4) << 3);                         \
        GLOAD_LDS16(SRC + (size_t)((ROFF) + row_) * K + (KT) * 64 + (cb_ >> 1),\
                    (char*)&L[BUF][PART][0] + c_ * 16); } }

    f32x4 acc[8][4];
#pragma unroll
    for (int i = 0; i < 8; ++i)
#pragma unroll
        for (int j = 0; j < 4; ++j) acc[i][j] = (f32x4)0.f;

    const int nt = K >> 6;   // 12

    // B-read coords (compile-time-ish per wave)
    const int bpart = 2 + (wn >> 1);
    const int bro = (wn & 1) * 64;
    const char* const abase = (const char*)&L[0][wm][0];
    const char* const bbase = (const char*)&L[0][bpart][0];
    const int bufstride = (int)((char*)&L[1][0][0] - (char*)&L[0][0][0]);

    // prologue: stage tile 0 fully
    STG(0, 2, W, f0, 0); STG(0, 3, W, f0 + 128, 0);
    STG(0, 0, A, m0, 0); STG(0, 1, A, m0 + 128, 0);
    VMC0; GBAR;

    short8 b[2][4];

    for (int t = 0; t < nt; ++t) {
        const int bo = (t & 1) * bufstride;
        const int nb = (t & 1) ^ 1;
        const bool st = (t + 1 < nt);

        // ---------- phase 0 (mh=0): read B (all) + A-half0, stage next B ----------
        short8 a[2][4];
#pragma unroll
        for (int kk = 0; kk < 2; ++kk) {
#pragma unroll
            for (int ni = 0; ni < 4; ++ni)
                b[kk][ni] = *reinterpret_cast<const short8*>(
                    bbase + bo + (bro + ni * 16 + lo) * 128 + ((kk * 64 + hi * 16) ^ csw));
#pragma unroll
            for (int mi = 0; mi < 4; ++mi)
                a[kk][mi] = *reinterpret_cast<const short8*>(
                    abase + bo + (mi * 16 + lo) * 128 + ((kk * 64 + hi * 16) ^ csw));
        }
        if (st) { STG(nb, 2, W, f0, t + 1); STG(nb, 3, W, f0 + 128, t + 1); }
        GBAR;
        LGKM0;
        __builtin_amdgcn_sched_barrier(0);
        __builtin_amdgcn_s_setprio(1);
#pragma unroll
        for (int kk = 0; kk < 2; ++kk)
#pragma unroll
            for (int mi = 0; mi < 4; ++mi)
#pragma unroll
                for (int ni = 0; ni < 4; ++ni)
                    acc[mi][ni] = __builtin_amdgcn_mfma_f32_16x16x32_bf16(
                        a[kk][mi], b[kk][ni], acc[mi][ni], 0, 0, 0);
        __builtin_amdgcn_s_setprio(0);
        VMC4; GBAR;

        // ---------- phase 1 (mh=1): read A-half1, stage next A ----------
#pragma unroll
        for (int kk = 0; kk < 2; ++kk)
#pragma unroll
            for (int mi = 0; mi < 4; ++mi)
                a[kk][mi] = *reinterpret_cast<const short8*>(
                    abase + bo + (64 + mi * 16 + lo) * 128 + ((kk * 64 + hi * 16) ^ csw));
        if (st) { STG(nb, 0, A, m0, t + 1); STG(nb, 1, A, m0 + 128, t + 1); }
        GBAR;
        LGKM0;
        __builtin_amdgcn_sched_barrier(0);
        __builtin_amdgcn_s_setprio(1);
#pragma unroll
        for (int kk = 0; kk < 2; ++kk)
#pragma unroll
            for (int mi = 0; mi < 4; ++mi)
#pragma unroll
                for (int ni = 0; ni < 4; ++ni)
                    acc[4 + mi][ni] = __builtin_amdgcn_mfma_f32_16x16x32_bf16(
                        a[kk][mi], b[kk][ni], acc[4 + mi][ni], 0, 0, 0);
        __builtin_amdgcn_s_setprio(0);
        if (st) { VMC2; } else { VMC0; }
        GBAR;
    }

    // -------- epilogue: QKV scatter. m = m0+wm*128+ai*16+hi*4+r, f = f0+wn*64+ni*16+lo
#pragma unroll
    for (int ai = 0; ai < 8; ++ai) {
#pragma unroll
        for (int ni = 0; ni < 4; ++ni) {
            int f = f0 + wn * 64 + ni * 16 + lo;
            float bv = bias[f];
#pragma unroll
            for (int r = 0; r < 4; ++r) {
                int m = m0 + wm * 128 + ai * 16 + hi * 4 + r;
                float val = acc[ai][ni][r] + bv;
                int b_ = m >> 10, n = m & 1023;
                if (f < 768) {
                    int h = f >> 6, d = f & 63;
                    qbuf[((size_t)(b_ * 12 + h) * 1024 + n) * 64 + d] = f2b(val * 0.125f);
                } else if (f < 1536) {
                    int f2 = f - 768; int h = f2 >> 6, d = f2 & 63;
                    kcbuf[((size_t)(b_ * 12 + h) * 1056 + 16 + n) * 64 + d] = f2b(val);
                } else {
                    int f2 = f - 1536; int h = f2 >> 6, d = f2 & 63;
                    vtbuf[((size_t)(b_ * 12 + h) * 64 + d) * 1056 + 16 + n] = f2b(val);
                }
            }
        }
    }
#undef STG
}

// ---------------- 128^2 ring-2 GEMM (round-5) for proj ----------------
template<int FT>
__global__ __launch_bounds__(256, 2) void gemm_dp(
    const unsigned short* __restrict__ A,
    const unsigned short* __restrict__ W,
    const float* __restrict__ bias,
    int M, int F, int K,
    float* __restrict__ fout)
{
    __shared__ __align__(16) unsigned short As[2][2][4096];
    __shared__ __align__(16) unsigned short Bs[2][2][4096];

    const int tid = threadIdx.x;
    const int bid = (blockIdx.x & 7) * (gridDim.x >> 3) + (blockIdx.x >> 3);
    const int m0 = (bid / FT) * 128;
    const int f0 = (bid % FT) * 128;
    const int wid = tid >> 6, lane = tid & 63;
    const int wr = wid >> 1, wc = wid & 1;
    const int lo = lane & 15, hi = lane >> 4;
    const int rdsw = ((hi ^ (lo & 3)) << 4);

#define STG(KT)                                                                  \
    { _Pragma("unroll") for (int kk_ = 0; kk_ < 2; ++kk_) {                      \
        _Pragma("unroll") for (int r_ = 0; r_ < 2; ++r_) {                       \
            int id_ = r_ * 256 + tid; int row_ = id_ >> 2;                       \
            int sc_ = (((id_ & 3) ^ (row_ & 3)) << 3);                           \
            GLOAD_LDS16(A + (size_t)(m0 + row_) * K + (KT) * 64 + kk_ * 32 + sc_,\
                        (char*)&As[(KT) & 1][kk_][0] + id_ * 16);                \
            GLOAD_LDS16(W + (size_t)(f0 + row_) * K + (KT) * 64 + kk_ * 32 + sc_,\
                        (char*)&Bs[(KT) & 1][kk_][0] + id_ * 16);                \
        } } }

    f32x4 acc[4][4];
#pragma unroll
    for (int i = 0; i < 4; ++i)
#pragma unroll
        for (int j = 0; j < 4; ++j) acc[i][j] = (f32x4)0.f;

    const int nt = K >> 6;

    STG(0);
    VMC0; GBAR;

    for (int t = 0; t < nt; ++t) {
        const int s = t & 1;
        if (t + 1 < nt) STG(t + 1);

        short8 av[2][4], bv[2][4];
#pragma unroll
        for (int kk = 0; kk < 2; ++kk)
#pragma unroll
            for (int i = 0; i < 4; ++i) {
                av[kk][i] = *reinterpret_cast<const short8*>(
                    (const char*)&As[s][kk][0] + (wr * 64 + i * 16 + lo) * 64 + rdsw);
                bv[kk][i] = *reinterpret_cast<const short8*>(
                    (const char*)&Bs[s][kk][0] + (wc * 64 + i * 16 + lo) * 64 + rdsw);
            }
        __builtin_amdgcn_s_setprio(1);
#pragma unroll
        for (int kk = 0; kk < 2; ++kk)
#pragma unroll
            for (int i = 0; i < 4; ++i)
#pragma unroll
                for (int j = 0; j < 4; ++j)
                    acc[i][j] = __builtin_amdgcn_mfma_f32_16x16x32_bf16(
                        av[kk][i], bv[kk][j], acc[i][j], 0, 0, 0);
        __builtin_amdgcn_s_setprio(0);

        if (t + 1 < nt) { VMC0; GBAR; }
    }

#pragma unroll
    for (int mi = 0; mi < 4; ++mi) {
#pragma unroll
        for (int ni = 0; ni < 4; ++ni) {
            int f = f0 + wc * 64 + ni * 16 + lo;
            float bv2 = bias[f];
#pragma unroll
            for (int r = 0; r < 4; ++r) {
                int m = m0 + wr * 64 + mi * 16 + hi * 4 + r;
                fout[(size_t)m * F + f] = acc[mi][ni][r] + bv2;
            }
        }
    }
#undef STG
}

// ---------------- flash attention: swapped-QK 32x32, 32 q-rows/wave ----------------
__global__ __launch_bounds__(256) void attn_kernel(
    const unsigned short* __restrict__ q,   // [96][1024][64] (pre-scaled by D^-0.5)
    const unsigned short* __restrict__ kc,  // [96][1056][64]
    const unsigned short* __restrict__ vT,  // [96][64][1056]
    unsigned short* __restrict__ ao)        // [8][1024][768]
{
    const int tid = threadIdx.x;
    const int w = tid >> 6, lane = tid & 63;
    const int ql = lane & 31;
    const int hi = lane >> 5;

    const int bid = (blockIdx.x & 7) * 96 + (blockIdx.x >> 3);
    const int head = bid >> 3;
    const int qt = (bid & 7) * 4 + w;
    const int b = head / 12, h = head % 12;

    const unsigned short* qp = q + ((size_t)head * 1024 + qt * 32) * 64;
    const unsigned short* kp = kc + (size_t)head * 1056 * 64;
    const unsigned short* vp = vT + (size_t)head * 64 * 1056;

    short8 qf[4];
#pragma unroll
    for (int ks = 0; ks < 4; ++ks)
        qf[ks] = *reinterpret_cast<const short8*>(qp + (size_t)ql * 64 + ks * 16 + hi * 8);

    f32x16 o0 = (f32x16)0.f, o1 = (f32x16)0.f;
    float m = -1e30f, l = 0.f;

    for (int t = 0; t < 33; ++t) {
        const int kbase = t * 32;
        f32x16 s = (f32x16)0.f;
        __builtin_amdgcn_s_setprio(1);
#pragma unroll
        for (int ks = 0; ks < 4; ++ks) {
            short8 kf = *reinterpret_cast<const short8*>(
                kp + (size_t)(kbase + ql) * 64 + ks * 16 + hi * 8);
            s = __builtin_amdgcn_mfma_f32_32x32x16_bf16(kf, qf[ks], s, 0, 0, 0);
        }
        __builtin_amdgcn_s_setprio(0);

        if (t == 32) {
#pragma unroll
            for (int r = 8; r < 16; ++r) s[r] = -1e30f;
        }

        float pmax = s[0];
#pragma unroll
        for (int r = 1; r < 16; ++r) pmax = fmaxf(pmax, s[r]);
        pmax = fmaxf(pmax, __shfl_xor(pmax, 32));
        if (!__all(pmax - m <= 8.f)) {
            float mn = fmaxf(m, pmax);
            float cf = __expf(m - mn);
            l *= cf;
            o0 *= cf;
            o1 *= cf;
            m = mn;
        }
        float p[16];
        float ts = 0.f;
#pragma unroll
        for (int r = 0; r < 16; ++r) { p[r] = __expf(s[r] - m); ts += p[r]; }
        ts += __shfl_xor(ts, 32);
        l += ts;

        int w0 = cvt_pk_bf16(p[0],  p[1]);
        int w1 = cvt_pk_bf16(p[2],  p[3]);
        int w2 = cvt_pk_bf16(p[4],  p[5]);
        int w3 = cvt_pk_bf16(p[6],  p[7]);
        int w4 = cvt_pk_bf16(p[8],  p[9]);
        int w5 = cvt_pk_bf16(p[10], p[11]);
        int w6 = cvt_pk_bf16(p[12], p[13]);
        int w7 = cvt_pk_bf16(p[14], p[15]);
        int x0 = __shfl_xor(w0, 32), x1 = __shfl_xor(w1, 32);
        int x2 = __shfl_xor(w2, 32), x3 = __shfl_xor(w3, 32);
        int x4 = __shfl_xor(w4, 32), x5 = __shfl_xor(w5, 32);
        int x6 = __shfl_xor(w6, 32), x7 = __shfl_xor(w7, 32);
        i32x4 pw0, pw1;
        pw0[0] = hi ? x2 : w0;  pw0[1] = hi ? x3 : w1;
        pw0[2] = hi ? w2 : x0;  pw0[3] = hi ? w3 : x1;
        pw1[0] = hi ? x6 : w4;  pw1[1] = hi ? x7 : w5;
        pw1[2] = hi ? w6 : x4;  pw1[3] = hi ? w7 : x5;
        short8 pf0 = __builtin_bit_cast(short8, pw0);
        short8 pf1 = __builtin_bit_cast(short8, pw1);

        short8 vf00 = *reinterpret_cast<const short8*>(vp + (size_t)ql * 1056 + kbase + hi * 8);
        short8 vf01 = *reinterpret_cast<const short8*>(vp + (size_t)ql * 1056 + kbase + 16 + hi * 8);
        short8 vf10 = *reinterpret_cast<const short8*>(vp + (size_t)(32 + ql) * 1056 + kbase + hi * 8);
        short8 vf11 = *reinterpret_cast<const short8*>(vp + (size_t)(32 + ql) * 1056 + kbase + 16 + hi * 8);
        __builtin_amdgcn_s_setprio(1);
        o0 = __builtin_amdgcn_mfma_f32_32x32x16_bf16(vf00, pf0, o0, 0, 0, 0);
        o0 = __builtin_amdgcn_mfma_f32_32x32x16_bf16(vf01, pf1, o0, 0, 0, 0);
        o1 = __builtin_amdgcn_mfma_f32_32x32x16_bf16(vf10, pf0, o1, 0, 0, 0);
        o1 = __builtin_amdgcn_mfma_f32_32x32x16_bf16(vf11, pf1, o1, 0, 0, 0);
        __builtin_amdgcn_s_setprio(0);
    }

    const float rinv = 1.f / l;
    unsigned short* aop = ao + ((size_t)b * 1024 + qt * 32 + ql) * 768 + h * 64;
#pragma unroll
    for (int r = 0; r < 16; r += 2) {
        int d = (r & 3) + 8 * (r >> 2) + 4 * hi;
        unsigned lo0 = f2b(o0[r] * rinv), lo1 = f2b(o0[r + 1] * rinv);
        *reinterpret_cast<unsigned*>(aop + d) = lo0 | (lo1 << 16);
        unsigned hi0 = f2b(o1[r] * rinv), hi1 = f2b(o1[r + 1] * rinv);
        *reinterpret_cast<unsigned*>(aop + 32 + d) = hi0 | (hi1 << 16);
    }
}

extern "C" void kernel_launch(void* const* d_in, const int* in_sizes, int n_in,
                              void* d_out, int out_size, void* d_ws, size_t ws_size,
                              hipStream_t stream) {
    const float* x        = (const float*)d_in[0];
    const float* qkv_w    = (const float*)d_in[1];
    const float* qkv_b    = (const float*)d_in[2];
    const float* proj_w   = (const float*)d_in[3];
    const float* proj_b   = (const float*)d_in[4];
    const float* prefix_k = (const float*)d_in[5];
    const float* prefix_v = (const float*)d_in[6];
    float* out = (float*)d_out;

    char* ws = (char*)d_ws;
    unsigned short* xb   = (unsigned short*)(ws);               // 8192*768 bf16
    unsigned short* wqkv = (unsigned short*)(ws + 12582912);    // 2304*768
    unsigned short* wp   = (unsigned short*)(ws + 16121856);    // 768*768
    unsigned short* qb   = (unsigned short*)(ws + 17301504);    // 96*1024*64
    unsigned short* kcb  = (unsigned short*)(ws + 29884416);    // 96*1056*64
    unsigned short* vtb  = (unsigned short*)(ws + 42860544);    // 96*64*1056
    unsigned short* aob  = xb;                                  // reuse xb after QKV GEMM

    cvt_f32_to_bf16<<<1024, 256, 0, stream>>>(x, xb, 8192 * 768 / 4);
    cvt_f32_to_bf16<<<512, 256, 0, stream>>>(qkv_w, wqkv, 2304 * 768 / 4);
    cvt_f32_to_bf16<<<256, 256, 0, stream>>>(proj_w, wp, 768 * 768 / 4);
    prefill<<<768, 256, 0, stream>>>(prefix_k, prefix_v, kcb, vtb);

    // QKV: 32 m-tiles (BM=256) x 9 f-tiles (BN=256) = 288 blocks (288%8==0)
    gemm256<9><<<288, 512, 0, stream>>>(xb, wqkv, qkv_b, 8192, 2304, 768,
                                        qb, kcb, vtb);
    attn_kernel<<<768, 256, 0, stream>>>(qb, kcb, vtb, aob);
    // proj: 64 m-tiles x 6 f-tiles = 384 blocks (384%8==0)
    gemm_dp<6><<<384, 256, 0, stream>>>(aob, wp, proj_b, 8192, 768, 768, out);
}

// Round 7
// 158.911 us; speedup vs baseline: 1.2567x; 1.2567x over previous
//
#include <hip/hip_runtime.h>

// Round 7: kill the epilogue scatters (schedule-invariant ~99us cap identified
//          as write-transaction bound, not K-loop bound):
//   - gemm MODE0: acc -> LDS tile (reusing staging LDS) -> coalesced 128B-run
//     stores; V^T produced by column reads of the LDS tile (no 2B scatter).
//   - attn: per-wave LDS bounce -> coalesced 64B/lane output rows.
//   - gemm256 (R6 regression) dropped; R5 ring-2 128^2 kernel for both GEMMs.
// Constants: B=8 N=1024 C=768 H=12 D=64 P=16; BH=96; padded KV MKV=1056.

typedef __attribute__((ext_vector_type(8))) short short8;
typedef __attribute__((ext_vector_type(4))) float f32x4;
typedef __attribute__((ext_vector_type(16))) float f32x16;
typedef __attribute__((ext_vector_type(4))) int i32x4;

#define GLOAD_LDS16(g, l)                                              \
    __builtin_amdgcn_global_load_lds(                                  \
        (const __attribute__((address_space(1))) void*)(g),            \
        (__attribute__((address_space(3))) void*)(l), 16, 0, 0)

#define GBAR  asm volatile("s_barrier" ::: "memory")
#define LGKM0 asm volatile("s_waitcnt lgkmcnt(0)" ::: "memory")
#define VMC0  asm volatile("s_waitcnt vmcnt(0)" ::: "memory")

__device__ __forceinline__ unsigned short f2b(float f) {
    unsigned u = __builtin_bit_cast(unsigned, f);
    u = (u + 0x7fffu + ((u >> 16) & 1u)) >> 16;
    return (unsigned short)u;
}

__device__ __forceinline__ int cvt_pk_bf16(float lo, float hi) {
    int r;
    asm("v_cvt_pk_bf16_f32 %0, %1, %2" : "=v"(r) : "v"(lo), "v"(hi));
    return r;
}

// ---------------- f32 -> bf16 convert (vectorized) ----------------
__global__ void cvt_f32_to_bf16(const float* __restrict__ in,
                                unsigned short* __restrict__ out, int n4) {
    int i = blockIdx.x * blockDim.x + threadIdx.x;
    int stride = gridDim.x * blockDim.x;
    for (; i < n4; i += stride) {
        float4 v = reinterpret_cast<const float4*>(in)[i];
        ushort4 o;
        o.x = f2b(v.x); o.y = f2b(v.y); o.z = f2b(v.z); o.w = f2b(v.w);
        reinterpret_cast<ushort4*>(out)[i] = o;
    }
}

// ------------- prefix K/V prefill + pad-row zeroing ----------------
__global__ void prefill(const float* __restrict__ pk, const float* __restrict__ pv,
                        unsigned short* __restrict__ kc, unsigned short* __restrict__ vT) {
    int idx = blockIdx.x * 256 + threadIdx.x;   // 96*32*64 total
    int d  = idx & 63;
    int j  = (idx >> 6) & 31;
    int bh = idx >> 11;
    if (bh >= 96) return;
    int h = bh % 12;
    if (j < 16) {
        kc[((size_t)bh * 1056 + j) * 64 + d]  = f2b(pk[j * 768 + h * 64 + d]);
        vT[((size_t)bh * 64 + d) * 1056 + j]  = f2b(pv[j * 768 + h * 64 + d]);
    } else {
        int row = 1040 + (j - 16);
        kc[((size_t)bh * 1056 + row) * 64 + d] = 0;
        vT[((size_t)bh * 64 + d) * 1056 + row] = 0;
    }
}

// ---------------- GEMM:  Y[m][f] = sum_k A[m][k] * W[f][k] + bias[f] ----------------
// BM=BN=128, BK=64, 256 threads = 4 waves (2x2), ring-2 LDS (64KB, 2 blocks/CU).
// MODE 0: QKV. Epilogue bounces the 128x128 output tile through the (dead)
//         staging LDS, then emits coalesced 128-B row segments; V-tiles are
//         read column-wise from LDS so V^T is written with contiguous runs.
// MODE 1: plain f32 row-major output (proj).
template<int MODE, int FT>
__global__ __launch_bounds__(256, 2) void gemm_dp(
    const unsigned short* __restrict__ A,   // [M][K] bf16
    const unsigned short* __restrict__ W,   // [F][K] bf16
    const float* __restrict__ bias,         // [F]
    int M, int F, int K,
    unsigned short* __restrict__ qbuf,      // [96][1024][64]
    unsigned short* __restrict__ kcbuf,     // [96][1056][64]
    unsigned short* __restrict__ vtbuf,     // [96][64][1056]
    float* __restrict__ fout)               // [M][F]
{
    __shared__ __align__(16) unsigned short SH[32768];   // 64 KB: staging, then out-tile
#define AS_(s, kk) (SH + (s) * 8192 + (kk) * 4096)
#define BS_(s, kk) (SH + 16384 + (s) * 8192 + (kk) * 4096)

    const int tid = threadIdx.x;
    const int bid = (blockIdx.x & 7) * (gridDim.x >> 3) + (blockIdx.x >> 3);
    const int m0 = (bid / FT) * 128;
    const int f0 = (bid % FT) * 128;
    const int wid = tid >> 6, lane = tid & 63;
    const int wr = wid >> 1, wc = wid & 1;
    const int lo = lane & 15, hi = lane >> 4;
    const int rdsw = ((hi ^ (lo & 3)) << 4);

#define STG(KT)                                                                  \
    { _Pragma("unroll") for (int kk_ = 0; kk_ < 2; ++kk_) {                      \
        _Pragma("unroll") for (int r_ = 0; r_ < 2; ++r_) {                       \
            int id_ = r_ * 256 + tid; int row_ = id_ >> 2;                       \
            int sc_ = (((id_ & 3) ^ (row_ & 3)) << 3);                           \
            GLOAD_LDS16(A + (size_t)(m0 + row_) * K + (KT) * 64 + kk_ * 32 + sc_,\
                        (char*)AS_((KT) & 1, kk_) + id_ * 16);                   \
            GLOAD_LDS16(W + (size_t)(f0 + row_) * K + (KT) * 64 + kk_ * 32 + sc_,\
                        (char*)BS_((KT) & 1, kk_) + id_ * 16);                   \
        } } }

    f32x4 acc[4][4];
#pragma unroll
    for (int i = 0; i < 4; ++i)
#pragma unroll
        for (int j = 0; j < 4; ++j) acc[i][j] = (f32x4)0.f;

    const int nt = K >> 6;

    STG(0);
    VMC0; GBAR;

    for (int t = 0; t < nt; ++t) {
        const int s = t & 1;
        if (t + 1 < nt) STG(t + 1);

        short8 av[2][4], bv[2][4];
#pragma unroll
        for (int kk = 0; kk < 2; ++kk)
#pragma unroll
            for (int i = 0; i < 4; ++i) {
                av[kk][i] = *reinterpret_cast<const short8*>(
                    (const char*)AS_(s, kk) + (wr * 64 + i * 16 + lo) * 64 + rdsw);
                bv[kk][i] = *reinterpret_cast<const short8*>(
                    (const char*)BS_(s, kk) + (wc * 64 + i * 16 + lo) * 64 + rdsw);
            }
        __builtin_amdgcn_s_setprio(1);
#pragma unroll
        for (int kk = 0; kk < 2; ++kk)
#pragma unroll
            for (int i = 0; i < 4; ++i)
#pragma unroll
                for (int j = 0; j < 4; ++j)
                    acc[i][j] = __builtin_amdgcn_mfma_f32_16x16x32_bf16(
                        av[kk][i], bv[kk][j], acc[i][j], 0, 0, 0);
        __builtin_amdgcn_s_setprio(0);

        if (t + 1 < nt) { VMC0; GBAR; }
    }

    if (MODE == 1) {
        // proj: direct coalesced f32 stores
#pragma unroll
        for (int mi = 0; mi < 4; ++mi) {
#pragma unroll
            for (int ni = 0; ni < 4; ++ni) {
                int f = f0 + wc * 64 + ni * 16 + lo;
                float bv2 = bias[f];
#pragma unroll
                for (int r = 0; r < 4; ++r) {
                    int m = m0 + wr * 64 + mi * 16 + hi * 4 + r;
                    fout[(size_t)m * F + f] = acc[mi][ni][r] + bv2;
                }
            }
        }
    } else {
        // ---- E1: acc (+bias, Q-scale) -> LDS tile [128 m][128 f], stride 136 ----
        __syncthreads();     // all waves done with staging LDS
        const float sc = (f0 < 768) ? 0.125f : 1.f;
#pragma unroll
        for (int mi = 0; mi < 4; ++mi) {
#pragma unroll
            for (int ni = 0; ni < 4; ++ni) {
                int fc = wc * 64 + ni * 16 + lo;
                float bv2 = bias[f0 + fc];
#pragma unroll
                for (int r = 0; r < 4; ++r) {
                    int mr = wr * 64 + mi * 16 + hi * 4 + r;
                    SH[mr * 136 + fc] = f2b((acc[mi][ni][r] + bv2) * sc);
                }
            }
        }
        __syncthreads();

        // ---- E2: coalesced emission ----
        const int row2 = tid >> 1, half = tid & 1;
        const int b_ = m0 >> 10, n0 = m0 & 1023;
        if (f0 < 1536) {
            // Q or K: thread copies one 64-elem (128 B) row segment
            const unsigned short* src = SH + row2 * 136 + half * 64;
            unsigned short* dst;
            if (f0 < 768) {
                int h = (f0 >> 6) + half;
                dst = qbuf + (((size_t)(b_ * 12 + h) * 1024 + n0 + row2) << 6);
            } else {
                int h = ((f0 - 768) >> 6) + half;
                dst = kcbuf + (((size_t)(b_ * 12 + h) * 1056 + 16 + n0 + row2) << 6);
            }
#pragma unroll
            for (int c = 0; c < 8; ++c)
                *reinterpret_cast<short8*>(dst + c * 8) =
                    *reinterpret_cast<const short8*>(src + c * 8);
        } else {
            // V^T: thread owns one d-row (f-col of tile), reads LDS column,
            // writes contiguous 128 B of vtbuf row.
            int fv = f0 - 1536 + row2;
            int h = fv >> 6, d = fv & 63;
            unsigned short* dst = vtbuf + ((size_t)(b_ * 12 + h) * 64 + d) * 1056
                                  + 16 + n0 + half * 64;
#pragma unroll
            for (int c = 0; c < 8; ++c) {
                short8 v;
#pragma unroll
                for (int j = 0; j < 8; ++j)
                    v[j] = (short)SH[(half * 64 + c * 8 + j) * 136 + row2];
                *reinterpret_cast<short8*>(dst + c * 8) = v;
            }
        }
    }
#undef STG
#undef AS_
#undef BS_
}

// ---------------- flash attention: swapped-QK 32x32, 32 q-rows/wave ----------------
__global__ __launch_bounds__(256) void attn_kernel(
    const unsigned short* __restrict__ q,   // [96][1024][64] (pre-scaled by D^-0.5)
    const unsigned short* __restrict__ kc,  // [96][1056][64]
    const unsigned short* __restrict__ vT,  // [96][64][1056]
    unsigned short* __restrict__ ao)        // [8][1024][768]
{
    __shared__ __align__(16) unsigned short OT[4][32 * 72];  // per-wave bounce

    const int tid = threadIdx.x;
    const int w = tid >> 6, lane = tid & 63;
    const int ql = lane & 31;
    const int hi = lane >> 5;

    const int bid = (blockIdx.x & 7) * 96 + (blockIdx.x >> 3);
    const int head = bid >> 3;
    const int qt = (bid & 7) * 4 + w;
    const int b = head / 12, h = head % 12;

    const unsigned short* qp = q + ((size_t)head * 1024 + qt * 32) * 64;
    const unsigned short* kp = kc + (size_t)head * 1056 * 64;
    const unsigned short* vp = vT + (size_t)head * 64 * 1056;

    short8 qf[4];
#pragma unroll
    for (int ks = 0; ks < 4; ++ks)
        qf[ks] = *reinterpret_cast<const short8*>(qp + (size_t)ql * 64 + ks * 16 + hi * 8);

    f32x16 o0 = (f32x16)0.f, o1 = (f32x16)0.f;
    float m = -1e30f, l = 0.f;

    for (int t = 0; t < 33; ++t) {
        const int kbase = t * 32;
        f32x16 s = (f32x16)0.f;
        __builtin_amdgcn_s_setprio(1);
#pragma unroll
        for (int ks = 0; ks < 4; ++ks) {
            short8 kf = *reinterpret_cast<const short8*>(
                kp + (size_t)(kbase + ql) * 64 + ks * 16 + hi * 8);
            s = __builtin_amdgcn_mfma_f32_32x32x16_bf16(kf, qf[ks], s, 0, 0, 0);
        }
        __builtin_amdgcn_s_setprio(0);

        if (t == 32) {
#pragma unroll
            for (int r = 8; r < 16; ++r) s[r] = -1e30f;
        }

        float pmax = s[0];
#pragma unroll
        for (int r = 1; r < 16; ++r) pmax = fmaxf(pmax, s[r]);
        pmax = fmaxf(pmax, __shfl_xor(pmax, 32));
        if (!__all(pmax - m <= 8.f)) {       // defer-max (T13)
            float mn = fmaxf(m, pmax);
            float cf = __expf(m - mn);
            l *= cf;
            o0 *= cf;
            o1 *= cf;
            m = mn;
        }
        float p[16];
        float ts = 0.f;
#pragma unroll
        for (int r = 0; r < 16; ++r) { p[r] = __expf(s[r] - m); ts += p[r]; }
        ts += __shfl_xor(ts, 32);
        l += ts;

        int w0 = cvt_pk_bf16(p[0],  p[1]);
        int w1 = cvt_pk_bf16(p[2],  p[3]);
        int w2 = cvt_pk_bf16(p[4],  p[5]);
        int w3 = cvt_pk_bf16(p[6],  p[7]);
        int w4 = cvt_pk_bf16(p[8],  p[9]);
        int w5 = cvt_pk_bf16(p[10], p[11]);
        int w6 = cvt_pk_bf16(p[12], p[13]);
        int w7 = cvt_pk_bf16(p[14], p[15]);
        int x0 = __shfl_xor(w0, 32), x1 = __shfl_xor(w1, 32);
        int x2 = __shfl_xor(w2, 32), x3 = __shfl_xor(w3, 32);
        int x4 = __shfl_xor(w4, 32), x5 = __shfl_xor(w5, 32);
        int x6 = __shfl_xor(w6, 32), x7 = __shfl_xor(w7, 32);
        i32x4 pw0, pw1;
        pw0[0] = hi ? x2 : w0;  pw0[1] = hi ? x3 : w1;
        pw0[2] = hi ? w2 : x0;  pw0[3] = hi ? w3 : x1;
        pw1[0] = hi ? x6 : w4;  pw1[1] = hi ? x7 : w5;
        pw1[2] = hi ? w6 : x4;  pw1[3] = hi ? w7 : x5;
        short8 pf0 = __builtin_bit_cast(short8, pw0);
        short8 pf1 = __builtin_bit_cast(short8, pw1);

        short8 vf00 = *reinterpret_cast<const short8*>(vp + (size_t)ql * 1056 + kbase + hi * 8);
        short8 vf01 = *reinterpret_cast<const short8*>(vp + (size_t)ql * 1056 + kbase + 16 + hi * 8);
        short8 vf10 = *reinterpret_cast<const short8*>(vp + (size_t)(32 + ql) * 1056 + kbase + hi * 8);
        short8 vf11 = *reinterpret_cast<const short8*>(vp + (size_t)(32 + ql) * 1056 + kbase + 16 + hi * 8);
        __builtin_amdgcn_s_setprio(1);
        o0 = __builtin_amdgcn_mfma_f32_32x32x16_bf16(vf00, pf0, o0, 0, 0, 0);
        o0 = __builtin_amdgcn_mfma_f32_32x32x16_bf16(vf01, pf1, o0, 0, 0, 0);
        o1 = __builtin_amdgcn_mfma_f32_32x32x16_bf16(vf10, pf0, o1, 0, 0, 0);
        o1 = __builtin_amdgcn_mfma_f32_32x32x16_bf16(vf11, pf1, o1, 0, 0, 0);
        __builtin_amdgcn_s_setprio(0);
    }

    // ---- epilogue: wave-local LDS bounce -> coalesced row writes ----
    const float rinv = 1.f / l;
    unsigned short* ow = &OT[w][0];
#pragma unroll
    for (int r = 0; r < 16; r += 2) {
        int d = (r & 3) + 8 * (r >> 2) + 4 * hi;
        unsigned v0 = (unsigned)f2b(o0[r] * rinv) | ((unsigned)f2b(o0[r + 1] * rinv) << 16);
        *reinterpret_cast<unsigned*>(ow + ql * 72 + d) = v0;
        unsigned v1 = (unsigned)f2b(o1[r] * rinv) | ((unsigned)f2b(o1[r + 1] * rinv) << 16);
        *reinterpret_cast<unsigned*>(ow + ql * 72 + 32 + d) = v1;
    }
    LGKM0;                            // wave-local visibility; no barrier needed
    __builtin_amdgcn_sched_barrier(0);
    const int row2 = lane >> 1, half = lane & 1;
    unsigned short* dst = ao + ((size_t)b * 1024 + qt * 32 + row2) * 768 + h * 64 + half * 32;
    const unsigned short* src = ow + row2 * 72 + half * 32;
#pragma unroll
    for (int c = 0; c < 4; ++c)
        *reinterpret_cast<short8*>(dst + c * 8) =
            *reinterpret_cast<const short8*>(src + c * 8);
}

extern "C" void kernel_launch(void* const* d_in, const int* in_sizes, int n_in,
                              void* d_out, int out_size, void* d_ws, size_t ws_size,
                              hipStream_t stream) {
    const float* x        = (const float*)d_in[0];
    const float* qkv_w    = (const float*)d_in[1];
    const float* qkv_b    = (const float*)d_in[2];
    const float* proj_w   = (const float*)d_in[3];
    const float* proj_b   = (const float*)d_in[4];
    const float* prefix_k = (const float*)d_in[5];
    const float* prefix_v = (const float*)d_in[6];
    float* out = (float*)d_out;

    char* ws = (char*)d_ws;
    unsigned short* xb   = (unsigned short*)(ws);               // 8192*768 bf16
    unsigned short* wqkv = (unsigned short*)(ws + 12582912);    // 2304*768
    unsigned short* wp   = (unsigned short*)(ws + 16121856);    // 768*768
    unsigned short* qb   = (unsigned short*)(ws + 17301504);    // 96*1024*64
    unsigned short* kcb  = (unsigned short*)(ws + 29884416);    // 96*1056*64
    unsigned short* vtb  = (unsigned short*)(ws + 42860544);    // 96*64*1056
    unsigned short* aob  = xb;                                  // reuse xb after QKV GEMM

    cvt_f32_to_bf16<<<1024, 256, 0, stream>>>(x, xb, 8192 * 768 / 4);
    cvt_f32_to_bf16<<<512, 256, 0, stream>>>(qkv_w, wqkv, 2304 * 768 / 4);
    cvt_f32_to_bf16<<<256, 256, 0, stream>>>(proj_w, wp, 768 * 768 / 4);
    prefill<<<768, 256, 0, stream>>>(prefix_k, prefix_v, kcb, vtb);

    // QKV: 64 m-tiles x 18 f-tiles = 1152 blocks (1152%8==0)
    gemm_dp<0, 18><<<1152, 256, 0, stream>>>(xb, wqkv, qkv_b, 8192, 2304, 768,
                                             qb, kcb, vtb, nullptr);
    attn_kernel<<<768, 256, 0, stream>>>(qb, kcb, vtb, aob);
    // proj: 64 m-tiles x 6 f-tiles = 384 blocks (384%8==0)
    gemm_dp<1, 6><<<384, 256, 0, stream>>>(aob, wp, proj_b, 8192, 768, 768,
                                           nullptr, nullptr, nullptr, out);
}